// Round 5
// baseline (892.075 us; speedup 1.0000x reference)
//
#include <hip/hip_runtime.h>

#define N_NODES 10000
#define N_EDGES 320000
#define NE_TOT  330000   /* E + N */
#define NEG_SLOPE 0.2f
#define LN_EPS 1e-5f

/* workspace layout (bytes) */
#define OFF_CNT    0u         /* int[N]            */
#define OFF_FILL   40000u     /* int[N]            */
#define OFF_ROWPTR 80128u     /* int[N+1]          */
#define OFF_EIDS   120320u    /* int[E+N]          */
#define OFF_LATTR  1440512u   /* float[N*64]       */
#define OFF_XL     4000512u   /* float[N*256]      */
#define OFF_XR     14240512u  /* float[N*256]      */
#define OFF_LOG    24480512u  /* float[(E+N)*4]    */

typedef __bf16 bf16x8 __attribute__((ext_vector_type(8)));
typedef float  f32x16 __attribute__((ext_vector_type(16)));

__global__ void k_count(const int* __restrict__ ei, int* __restrict__ cnt) {
    int e = blockIdx.x * blockDim.x + threadIdx.x;
    if (e < N_EDGES) atomicAdd(&cnt[ei[N_EDGES + e]], 1);
}

__global__ void k_scan(const int* __restrict__ cnt, int* __restrict__ row_ptr) {
    __shared__ int sums[256];
    int t = threadIdx.x;
    const int CH = (N_NODES + 255) / 256;   /* 40 */
    int base = t * CH;
    int s = 0;
    for (int i = 0; i < CH; i++) {
        int n = base + i;
        if (n < N_NODES) s += cnt[n] + 1;   /* +1 self loop */
    }
    sums[t] = s;
    __syncthreads();
    for (int off = 1; off < 256; off <<= 1) {
        int v = (t >= off) ? sums[t - off] : 0;
        __syncthreads();
        sums[t] += v;
        __syncthreads();
    }
    int run = (t == 0) ? 0 : sums[t - 1];
    for (int i = 0; i < CH; i++) {
        int n = base + i;
        if (n < N_NODES) { row_ptr[n] = run; run += cnt[n] + 1; }
    }
    if (t == 255) row_ptr[N_NODES] = sums[255];
}

__global__ void k_fill(const int* __restrict__ ei, const int* __restrict__ row_ptr,
                       int* __restrict__ fill, int* __restrict__ eids) {
    int e = blockIdx.x * blockDim.x + threadIdx.x;
    if (e >= NE_TOT) return;
    int d = (e < N_EDGES) ? ei[N_EDGES + e] : (e - N_EDGES);
    int pos = atomicAdd(&fill[d], 1);
    eids[row_ptr[d] + pos] = e;
}

/* one wave per node: mean of incoming edge_attr; 4 rows in flight (unroll 4,
   branchless masked loads so iterations pipeline). */
__global__ void k_loop_attr(const float* __restrict__ edge_attr,
                            const int* __restrict__ row_ptr,
                            const int* __restrict__ eids,
                            const int* __restrict__ cnt,
                            float* __restrict__ lattr) {
    int node = (blockIdx.x << 2) + (threadIdx.x >> 6);
    int lane = threadIdx.x & 63;
    int b = row_ptr[node], en = row_ptr[node + 1];
    float s0 = 0.0f, s1 = 0.0f, s2 = 0.0f, s3 = 0.0f;
    int i = b;
    for (; i + 3 < en; i += 4) {
        int e0 = eids[i], e1 = eids[i + 1], e2 = eids[i + 2], e3 = eids[i + 3];
        int v0 = e0 < N_EDGES, v1 = e1 < N_EDGES, v2 = e2 < N_EDGES, v3 = e3 < N_EDGES;
        float a0 = edge_attr[(size_t)(v0 ? e0 : 0) * 64 + lane];
        float a1 = edge_attr[(size_t)(v1 ? e1 : 0) * 64 + lane];
        float a2 = edge_attr[(size_t)(v2 ? e2 : 0) * 64 + lane];
        float a3 = edge_attr[(size_t)(v3 ? e3 : 0) * 64 + lane];
        s0 += v0 ? a0 : 0.0f;
        s1 += v1 ? a1 : 0.0f;
        s2 += v2 ? a2 : 0.0f;
        s3 += v3 ? a3 : 0.0f;
    }
    for (; i < en; i++) {
        int e = eids[i];
        int v = e < N_EDGES;
        float a = edge_attr[(size_t)(v ? e : 0) * 64 + lane];
        s0 += v ? a : 0.0f;
    }
    float s = (s0 + s1) + (s2 + s3);
    float c = (float)cnt[node];
    lattr[node * 64 + lane] = s / fmaxf(c, 1.0f);
}

/* xl = x@Wl^T + bl ; xr = x@Wr^T + br.  8 nodes per 256-thread block. */
__global__ void k_gemm_xlxr(const float* __restrict__ x,
                            const float* __restrict__ Wl, const float* __restrict__ bl,
                            const float* __restrict__ Wr, const float* __restrict__ br,
                            float* __restrict__ xl, float* __restrict__ xr) {
    __shared__ float xs[8][256];
    int t = threadIdx.x;
    int nb = blockIdx.x * 8;
#pragma unroll
    for (int nn = 0; nn < 8; nn++) xs[nn][t] = x[(nb + nn) * 256 + t];
    __syncthreads();

    float accl[8], accr[8];
    float b0 = bl[t], b1 = br[t];
#pragma unroll
    for (int nn = 0; nn < 8; nn++) { accl[nn] = b0; accr[nn] = b1; }

    const float4* wl4 = reinterpret_cast<const float4*>(Wl) + t * 64;
    const float4* wr4 = reinterpret_cast<const float4*>(Wr) + t * 64;
    for (int i = 0; i < 64; i++) {
        float4 wl = wl4[i];
        float4 wr = wr4[i];
#pragma unroll
        for (int nn = 0; nn < 8; nn++) {
            float4 xv = reinterpret_cast<const float4*>(xs[nn])[i];
            accl[nn] = fmaf(xv.x, wl.x, accl[nn]);
            accl[nn] = fmaf(xv.y, wl.y, accl[nn]);
            accl[nn] = fmaf(xv.z, wl.z, accl[nn]);
            accl[nn] = fmaf(xv.w, wl.w, accl[nn]);
            accr[nn] = fmaf(xv.x, wr.x, accr[nn]);
            accr[nn] = fmaf(xv.y, wr.y, accr[nn]);
            accr[nn] = fmaf(xv.z, wr.z, accr[nn]);
            accr[nn] = fmaf(xv.w, wr.w, accr[nn]);
        }
    }
#pragma unroll
    for (int nn = 0; nn < 8; nn++) {
        xl[(nb + nn) * 256 + t] = accl[nn];
        xr[(nb + nn) * 256 + t] = accr[nn];
    }
}

/* logits via operand-swapped MFMA (acc = We * ea^T = ep^T); lane ln31 holds
   edge t0+ln31's c-values in-register.  __launch_bounds__(256,4) caps VGPRs
   at 128 -> 4 waves/SIMD (latency hiding was the round-4 bottleneck at 208
   VGPR / 2 waves).  att staged in LDS.  One tile per wave (grid 2579). */
__global__ __launch_bounds__(256, 4) void k_logits_mfma(
        const int* __restrict__ ei,
        const float* __restrict__ edge_attr,
        const float* __restrict__ lattr,
        const float* __restrict__ xl, const float* __restrict__ xr,
        const float* __restrict__ We, const float* __restrict__ att,
        float* __restrict__ logits) {
    __shared__ __bf16 fb[32 * 64 * 8];   /* [frag f=g*4+ks][lane][8], 32 KB */
    __shared__ float att_s[256];
    int tid = threadIdx.x;

    /* build We fragments (We is [c=256][k=64] row-major) */
    for (int idx = tid; idx < 2048; idx += 256) {
        int f = idx >> 6, ls = idx & 63;
        int g = f >> 2, ks = f & 3;
        int c = g * 32 + (ls & 31);
        int kb = ks * 16 + (ls >> 5) * 8;
        const float* w = We + c * 64 + kb;
        float4 a0 = *reinterpret_cast<const float4*>(w);
        float4 a1 = *reinterpret_cast<const float4*>(w + 4);
        bf16x8 t;
        t[0] = (__bf16)a0.x; t[1] = (__bf16)a0.y; t[2] = (__bf16)a0.z; t[3] = (__bf16)a0.w;
        t[4] = (__bf16)a1.x; t[5] = (__bf16)a1.y; t[6] = (__bf16)a1.z; t[7] = (__bf16)a1.w;
        *reinterpret_cast<bf16x8*>(&fb[idx * 8]) = t;
    }
    if (tid < 64) {
        reinterpret_cast<float4*>(att_s)[tid] =
            reinterpret_cast<const float4*>(att)[tid];
    }
    __syncthreads();

    int lane = tid & 63;
    int wv = tid >> 6;
    int half = lane >> 5;
    int ln31 = lane & 31;

    const int ntiles = (NE_TOT + 31) / 32;   /* 10313 */
    for (int t = blockIdx.x * 4 + wv; t < ntiles; t += gridDim.x * 4) {
        int t0 = t * 32;
        int e = t0 + ln31;
        int ec = (e < NE_TOT) ? e : (NE_TOT - 1);
        int s, d;
        const float* row;
        if (ec < N_EDGES) {
            s = ei[ec]; d = ei[N_EDGES + ec];
            row = edge_attr + (size_t)ec * 64;
        } else {
            s = ec - N_EDGES; d = s;
            row = lattr + (size_t)(ec - N_EDGES) * 64;
        }

        /* B fragments: lane holds edge (ln31)'s ea[k], k = half*8 + ks*16 + j */
        bf16x8 af[4];
#pragma unroll
        for (int ks = 0; ks < 4; ks++) {
            const float* p = row + half * 8 + ks * 16;
            float4 v0 = *reinterpret_cast<const float4*>(p);
            float4 v1 = *reinterpret_cast<const float4*>(p + 4);
            af[ks][0] = (__bf16)v0.x; af[ks][1] = (__bf16)v0.y;
            af[ks][2] = (__bf16)v0.z; af[ks][3] = (__bf16)v0.w;
            af[ks][4] = (__bf16)v1.x; af[ks][5] = (__bf16)v1.y;
            af[ks][6] = (__bf16)v1.z; af[ks][7] = (__bf16)v1.w;
        }

        const float* xls = xl + (size_t)s * 256;
        const float* xrd = xr + (size_t)d * 256;

        float hsum[4] = {0.0f, 0.0f, 0.0f, 0.0f};
#pragma unroll
        for (int g = 0; g < 8; g++) {       /* 32-c block; head = g>>1 */
            f32x16 acc;
#pragma unroll
            for (int j = 0; j < 16; j++) acc[j] = 0.0f;
#pragma unroll
            for (int ks = 0; ks < 4; ks++) {
                bf16x8 wfr = *reinterpret_cast<const bf16x8*>(
                    &fb[(((g * 4 + ks) * 64) + lane) * 8]);
                acc = __builtin_amdgcn_mfma_f32_32x32x16_bf16(wfr, af[ks], acc, 0, 0, 0);
            }
            int cb0 = g * 32 + 4 * half;
            float hs = 0.0f;
#pragma unroll
            for (int q = 0; q < 4; q++) {   /* c chunk: cb0 + 8q .. +4 */
                int cb = cb0 + 8 * q;
                float4 xa = *reinterpret_cast<const float4*>(xls + cb);
                float4 xb = *reinterpret_cast<const float4*>(xrd + cb);
                float4 at = *reinterpret_cast<const float4*>(&att_s[cb]);
                const float* ap = reinterpret_cast<const float*>(&xa);
                const float* bp = reinterpret_cast<const float*>(&xb);
                const float* tp = reinterpret_cast<const float*>(&at);
#pragma unroll
                for (int j = 0; j < 4; j++) {
                    float v = acc[q * 4 + j] + ap[j] + bp[j];
                    v = (v >= 0.0f) ? v : NEG_SLOPE * v;
                    hs = fmaf(v, tp[j], hs);
                }
            }
            hsum[g >> 1] += hs;
        }
#pragma unroll
        for (int hh = 0; hh < 4; hh++) hsum[hh] += __shfl_xor(hsum[hh], 32, 64);
        if (half == 0 && e < NE_TOT) {
            reinterpret_cast<float4*>(logits)[e] =
                make_float4(hsum[0], hsum[1], hsum[2], hsum[3]);
        }
    }
}

/* one wave per node: segment softmax + weighted sum + bias + SiLU + LayerNorm.
   3 passes, each unrolled so loads pipeline (independent iterations). */
__global__ void k_aggregate(const int* __restrict__ ei,
                            const int* __restrict__ row_ptr,
                            const int* __restrict__ eids,
                            const float* __restrict__ logits,
                            const float* __restrict__ xl,
                            const float* __restrict__ bias,
                            const float* __restrict__ gamma,
                            const float* __restrict__ beta,
                            float* __restrict__ hout,
                            float* __restrict__ alpha_out) {
    int node = (blockIdx.x << 2) + (threadIdx.x >> 6);
    int lane = threadIdx.x & 63;
    int h = lane >> 4;
    int b = row_ptr[node], en = row_ptr[node + 1];

    /* pass 1: max (4 independent partials) */
    float m0 = -INFINITY, m1 = -INFINITY, m2 = -INFINITY, m3 = -INFINITY;
    int i = b;
    for (; i + 3 < en; i += 4) {
        int e0 = eids[i], e1 = eids[i + 1], e2 = eids[i + 2], e3 = eids[i + 3];
        m0 = fmaxf(m0, logits[e0 * 4 + h]);
        m1 = fmaxf(m1, logits[e1 * 4 + h]);
        m2 = fmaxf(m2, logits[e2 * 4 + h]);
        m3 = fmaxf(m3, logits[e3 * 4 + h]);
    }
    for (; i < en; i++) m0 = fmaxf(m0, logits[eids[i] * 4 + h]);
    float mh = fmaxf(fmaxf(m0, m1), fmaxf(m2, m3));

    /* pass 2: denom (4 independent partials) */
    float d0 = 0.0f, d1 = 0.0f, d2 = 0.0f, d3 = 0.0f;
    i = b;
    for (; i + 3 < en; i += 4) {
        int e0 = eids[i], e1 = eids[i + 1], e2 = eids[i + 2], e3 = eids[i + 3];
        d0 += __expf(logits[e0 * 4 + h] - mh);
        d1 += __expf(logits[e1 * 4 + h] - mh);
        d2 += __expf(logits[e2 * 4 + h] - mh);
        d3 += __expf(logits[e3 * 4 + h] - mh);
    }
    for (; i < en; i++) d0 += __expf(logits[eids[i] * 4 + h] - mh);
    float rden = 1.0f / ((d0 + d1) + (d2 + d3));

    /* pass 3: alpha + weighted gather (2 accumulators) */
    const float4* xl4p = reinterpret_cast<const float4*>(xl);
    float4 acc; acc.x = acc.y = acc.z = acc.w = 0.0f;
    float4 ac2; ac2.x = ac2.y = ac2.z = ac2.w = 0.0f;
    i = b;
    for (; i + 1 < en; i += 2) {
        int e0 = eids[i], e1 = eids[i + 1];
        float al0 = __expf(logits[e0 * 4 + h] - mh) * rden;
        float al1 = __expf(logits[e1 * 4 + h] - mh) * rden;
        if ((lane & 15) == 0) {
            alpha_out[e0 * 4 + h] = al0;
            alpha_out[e1 * 4 + h] = al1;
        }
        int s0 = (e0 < N_EDGES) ? ei[e0] : (e0 - N_EDGES);
        int s1 = (e1 < N_EDGES) ? ei[e1] : (e1 - N_EDGES);
        float4 xv0 = xl4p[s0 * 64 + lane];
        float4 xv1 = xl4p[s1 * 64 + lane];
        acc.x = fmaf(al0, xv0.x, acc.x);
        acc.y = fmaf(al0, xv0.y, acc.y);
        acc.z = fmaf(al0, xv0.z, acc.z);
        acc.w = fmaf(al0, xv0.w, acc.w);
        ac2.x = fmaf(al1, xv1.x, ac2.x);
        ac2.y = fmaf(al1, xv1.y, ac2.y);
        ac2.z = fmaf(al1, xv1.z, ac2.z);
        ac2.w = fmaf(al1, xv1.w, ac2.w);
    }
    for (; i < en; i++) {
        int e = eids[i];
        float al = __expf(logits[e * 4 + h] - mh) * rden;
        if ((lane & 15) == 0) alpha_out[e * 4 + h] = al;
        int s = (e < N_EDGES) ? ei[e] : (e - N_EDGES);
        float4 xv = xl4p[s * 64 + lane];
        acc.x = fmaf(al, xv.x, acc.x);
        acc.y = fmaf(al, xv.y, acc.y);
        acc.z = fmaf(al, xv.z, acc.z);
        acc.w = fmaf(al, xv.w, acc.w);
    }
    acc.x += ac2.x; acc.y += ac2.y; acc.z += ac2.z; acc.w += ac2.w;

    const float4 b4 = reinterpret_cast<const float4*>(bias)[lane];
    float4 hv;
    hv.x = acc.x + b4.x; hv.y = acc.y + b4.y;
    hv.z = acc.z + b4.z; hv.w = acc.w + b4.w;
    /* SiLU */
    hv.x = hv.x / (1.0f + __expf(-hv.x));
    hv.y = hv.y / (1.0f + __expf(-hv.y));
    hv.z = hv.z / (1.0f + __expf(-hv.z));
    hv.w = hv.w / (1.0f + __expf(-hv.w));
    /* LayerNorm over 256 dims spread across 64 lanes x 4 */
    float s1 = hv.x + hv.y + hv.z + hv.w;
    float s2 = hv.x * hv.x + hv.y * hv.y + hv.z * hv.z + hv.w * hv.w;
#pragma unroll
    for (int off = 1; off < 64; off <<= 1) {
        s1 += __shfl_xor(s1, off, 64);
        s2 += __shfl_xor(s2, off, 64);
    }
    float mu = s1 * (1.0f / 256.0f);
    float var = s2 * (1.0f / 256.0f) - mu * mu;
    float rs = rsqrtf(var + LN_EPS);
    const float4 g4 = reinterpret_cast<const float4*>(gamma)[lane];
    const float4 be4 = reinterpret_cast<const float4*>(beta)[lane];
    float4 o;
    o.x = (hv.x - mu) * rs * g4.x + be4.x;
    o.y = (hv.y - mu) * rs * g4.y + be4.y;
    o.z = (hv.z - mu) * rs * g4.z + be4.z;
    o.w = (hv.w - mu) * rs * g4.w + be4.w;
    reinterpret_cast<float4*>(hout)[node * 64 + lane] = o;
}

extern "C" void kernel_launch(void* const* d_in, const int* in_sizes, int n_in,
                              void* d_out, int out_size, void* d_ws, size_t ws_size,
                              hipStream_t stream) {
    (void)in_sizes; (void)n_in; (void)out_size; (void)ws_size;
    const float* x         = (const float*)d_in[0];
    const int*   ei        = (const int*)d_in[1];
    const float* edge_attr = (const float*)d_in[2];
    const float* Wl        = (const float*)d_in[3];
    const float* bl        = (const float*)d_in[4];
    const float* Wr        = (const float*)d_in[5];
    const float* br        = (const float*)d_in[6];
    const float* We        = (const float*)d_in[7];
    const float* att       = (const float*)d_in[8];
    const float* bias      = (const float*)d_in[9];
    const float* gamma     = (const float*)d_in[10];
    const float* beta      = (const float*)d_in[11];

    char* ws = (char*)d_ws;
    int*   cnt     = (int*)(ws + OFF_CNT);
    int*   fill    = (int*)(ws + OFF_FILL);
    int*   row_ptr = (int*)(ws + OFF_ROWPTR);
    int*   eids    = (int*)(ws + OFF_EIDS);
    float* lattr   = (float*)(ws + OFF_LATTR);
    float* xl      = (float*)(ws + OFF_XL);
    float* xr      = (float*)(ws + OFF_XR);
    float* logits  = (float*)(ws + OFF_LOG);

    float* hout      = (float*)d_out;
    float* alpha_out = (float*)d_out + N_NODES * 256;

    hipMemsetAsync(ws + OFF_CNT, 0, 2 * N_NODES * sizeof(int), stream);

    k_count<<<(N_EDGES + 255) / 256, 256, 0, stream>>>(ei, cnt);
    k_scan<<<1, 256, 0, stream>>>(cnt, row_ptr);
    k_fill<<<(NE_TOT + 255) / 256, 256, 0, stream>>>(ei, row_ptr, fill, eids);
    k_loop_attr<<<N_NODES / 4, 256, 0, stream>>>(edge_attr, row_ptr, eids, cnt, lattr);
    k_gemm_xlxr<<<N_NODES / 8, 256, 0, stream>>>(x, Wl, bl, Wr, br, xl, xr);
    k_logits_mfma<<<2579, 256, 0, stream>>>(ei, edge_attr, lattr, xl, xr, We, att, logits);
    k_aggregate<<<N_NODES / 4, 256, 0, stream>>>(ei, row_ptr, eids, logits, xl,
                                                 bias, gamma, beta, hout, alpha_out);
}

// Round 6
// 569.980 us; speedup vs baseline: 1.5651x; 1.5651x over previous
//
#include <hip/hip_runtime.h>

#define N_NODES 10000
#define N_EDGES 320000
#define NE_TOT  330000   /* E + N */
#define NEG_SLOPE 0.2f
#define LN_EPS 1e-5f

/* workspace layout (bytes) */
#define OFF_CNT    0u         /* int[N]            */
#define OFF_FILL   40000u     /* int[N]            */
#define OFF_ROWPTR 80128u     /* int[N+1]          */
#define OFF_EIDS   120320u    /* int[E+N]          */
#define OFF_LATTR  1440512u   /* float[N*64]       */
#define OFF_XL     4000512u   /* float[N*256]      */
#define OFF_XR     14240512u  /* float[N*256]      */
#define OFF_LOG    24480512u  /* float[(E+N)*4]    */

typedef __bf16 bf16x8 __attribute__((ext_vector_type(8)));
typedef float  f32x4  __attribute__((ext_vector_type(4)));

__global__ void k_count(const int* __restrict__ ei, int* __restrict__ cnt) {
    int e = blockIdx.x * blockDim.x + threadIdx.x;
    if (e < N_EDGES) atomicAdd(&cnt[ei[N_EDGES + e]], 1);
}

__global__ void k_scan(const int* __restrict__ cnt, int* __restrict__ row_ptr) {
    __shared__ int sums[256];
    int t = threadIdx.x;
    const int CH = (N_NODES + 255) / 256;   /* 40 */
    int base = t * CH;
    int s = 0;
    for (int i = 0; i < CH; i++) {
        int n = base + i;
        if (n < N_NODES) s += cnt[n] + 1;   /* +1 self loop */
    }
    sums[t] = s;
    __syncthreads();
    for (int off = 1; off < 256; off <<= 1) {
        int v = (t >= off) ? sums[t - off] : 0;
        __syncthreads();
        sums[t] += v;
        __syncthreads();
    }
    int run = (t == 0) ? 0 : sums[t - 1];
    for (int i = 0; i < CH; i++) {
        int n = base + i;
        if (n < N_NODES) { row_ptr[n] = run; run += cnt[n] + 1; }
    }
    if (t == 255) row_ptr[N_NODES] = sums[255];
}

__global__ void k_fill(const int* __restrict__ ei, const int* __restrict__ row_ptr,
                       int* __restrict__ fill, int* __restrict__ eids) {
    int e = blockIdx.x * blockDim.x + threadIdx.x;
    if (e >= NE_TOT) return;
    int d = (e < N_EDGES) ? ei[N_EDGES + e] : (e - N_EDGES);
    int pos = atomicAdd(&fill[d], 1);
    eids[row_ptr[d] + pos] = e;
}

/* one wave per node: mean of incoming edge_attr; 4 rows in flight (unroll 4,
   branchless masked loads so iterations pipeline). */
__global__ void k_loop_attr(const float* __restrict__ edge_attr,
                            const int* __restrict__ row_ptr,
                            const int* __restrict__ eids,
                            const int* __restrict__ cnt,
                            float* __restrict__ lattr) {
    int node = (blockIdx.x << 2) + (threadIdx.x >> 6);
    int lane = threadIdx.x & 63;
    int b = row_ptr[node], en = row_ptr[node + 1];
    float s0 = 0.0f, s1 = 0.0f, s2 = 0.0f, s3 = 0.0f;
    int i = b;
    for (; i + 3 < en; i += 4) {
        int e0 = eids[i], e1 = eids[i + 1], e2 = eids[i + 2], e3 = eids[i + 3];
        int v0 = e0 < N_EDGES, v1 = e1 < N_EDGES, v2 = e2 < N_EDGES, v3 = e3 < N_EDGES;
        float a0 = edge_attr[(size_t)(v0 ? e0 : 0) * 64 + lane];
        float a1 = edge_attr[(size_t)(v1 ? e1 : 0) * 64 + lane];
        float a2 = edge_attr[(size_t)(v2 ? e2 : 0) * 64 + lane];
        float a3 = edge_attr[(size_t)(v3 ? e3 : 0) * 64 + lane];
        s0 += v0 ? a0 : 0.0f;
        s1 += v1 ? a1 : 0.0f;
        s2 += v2 ? a2 : 0.0f;
        s3 += v3 ? a3 : 0.0f;
    }
    for (; i < en; i++) {
        int e = eids[i];
        int v = e < N_EDGES;
        float a = edge_attr[(size_t)(v ? e : 0) * 64 + lane];
        s0 += v ? a : 0.0f;
    }
    float s = (s0 + s1) + (s2 + s3);
    float c = (float)cnt[node];
    lattr[node * 64 + lane] = s / fmaxf(c, 1.0f);
}

/* xl = x@Wl^T + bl ; xr = x@Wr^T + br.  8 nodes per 256-thread block. */
__global__ void k_gemm_xlxr(const float* __restrict__ x,
                            const float* __restrict__ Wl, const float* __restrict__ bl,
                            const float* __restrict__ Wr, const float* __restrict__ br,
                            float* __restrict__ xl, float* __restrict__ xr) {
    __shared__ float xs[8][256];
    int t = threadIdx.x;
    int nb = blockIdx.x * 8;
#pragma unroll
    for (int nn = 0; nn < 8; nn++) xs[nn][t] = x[(nb + nn) * 256 + t];
    __syncthreads();

    float accl[8], accr[8];
    float b0 = bl[t], b1 = br[t];
#pragma unroll
    for (int nn = 0; nn < 8; nn++) { accl[nn] = b0; accr[nn] = b1; }

    const float4* wl4 = reinterpret_cast<const float4*>(Wl) + t * 64;
    const float4* wr4 = reinterpret_cast<const float4*>(Wr) + t * 64;
    for (int i = 0; i < 64; i++) {
        float4 wl = wl4[i];
        float4 wr = wr4[i];
#pragma unroll
        for (int nn = 0; nn < 8; nn++) {
            float4 xv = reinterpret_cast<const float4*>(xs[nn])[i];
            accl[nn] = fmaf(xv.x, wl.x, accl[nn]);
            accl[nn] = fmaf(xv.y, wl.y, accl[nn]);
            accl[nn] = fmaf(xv.z, wl.z, accl[nn]);
            accl[nn] = fmaf(xv.w, wl.w, accl[nn]);
            accr[nn] = fmaf(xv.x, wr.x, accr[nn]);
            accr[nn] = fmaf(xv.y, wr.y, accr[nn]);
            accr[nn] = fmaf(xv.z, wr.z, accr[nn]);
            accr[nn] = fmaf(xv.w, wr.w, accr[nn]);
        }
    }
#pragma unroll
    for (int nn = 0; nn < 8; nn++) {
        xl[(nb + nn) * 256 + t] = accl[nn];
        xr[(nb + nn) * 256 + t] = accr[nn];
    }
}

/* logits via operand-swapped 16x16x32 MFMA: one wave = 16-edge tile.
   acc = We_frag (A, m=c) * ea_frag (B, n=edge); C: col=lane&15 (edge),
   row=(lane>>4)*4+r (c within 16-block) -> small register footprint
   (acc 4, ea frags 8) so occupancy is NOT forced (round-5's cap spilled).
   A[m=lane&15][k=(lane>>4)*8+j], B[k=(lane>>4)*8+j][n=lane&15]. */
__global__ __launch_bounds__(256) void k_logits_mfma(
        const int* __restrict__ ei,
        const float* __restrict__ edge_attr,
        const float* __restrict__ lattr,
        const float* __restrict__ xl, const float* __restrict__ xr,
        const float* __restrict__ We, const float* __restrict__ att,
        float* __restrict__ logits) {
    __shared__ __bf16 fb[32 * 64 * 8];   /* [f=cb*2+step][lane][8], 32 KB */
    __shared__ float att_s[256];
    int tid = threadIdx.x;

    /* build We fragments (We is [c=256][k=64] row-major) */
    for (int idx = tid; idx < 2048; idx += 256) {
        int f = idx >> 6, ls = idx & 63;
        int cb = f >> 1, step = f & 1;
        int c = cb * 16 + (ls & 15);
        int k = step * 32 + (ls >> 4) * 8;
        const float* w = We + c * 64 + k;
        float4 a0 = *reinterpret_cast<const float4*>(w);
        float4 a1 = *reinterpret_cast<const float4*>(w + 4);
        bf16x8 t;
        t[0] = (__bf16)a0.x; t[1] = (__bf16)a0.y; t[2] = (__bf16)a0.z; t[3] = (__bf16)a0.w;
        t[4] = (__bf16)a1.x; t[5] = (__bf16)a1.y; t[6] = (__bf16)a1.z; t[7] = (__bf16)a1.w;
        *reinterpret_cast<bf16x8*>(&fb[idx * 8]) = t;
    }
    if (tid < 64) {
        reinterpret_cast<float4*>(att_s)[tid] =
            reinterpret_cast<const float4*>(att)[tid];
    }
    __syncthreads();

    int lane = tid & 63;
    int wv = tid >> 6;
    int quad = lane >> 4;
    int ln15 = lane & 15;

    const int ntiles = (NE_TOT + 15) / 16;   /* 20625 */
    for (int t = blockIdx.x * 4 + wv; t < ntiles; t += gridDim.x * 4) {
        int t0 = t * 16;
        int e = t0 + ln15;
        int ec = (e < NE_TOT) ? e : (NE_TOT - 1);
        int s, d;
        const float* row;
        if (ec < N_EDGES) {
            s = ei[ec]; d = ei[N_EDGES + ec];
            row = edge_attr + (size_t)ec * 64;
        } else {
            s = ec - N_EDGES; d = s;
            row = lattr + (size_t)(ec - N_EDGES) * 64;
        }

        /* B fragments: lane holds edge ln15's ea[k], k = step*32 + quad*8 + j */
        bf16x8 bfr[2];
#pragma unroll
        for (int step = 0; step < 2; step++) {
            const float* p = row + step * 32 + quad * 8;
            float4 v0 = *reinterpret_cast<const float4*>(p);
            float4 v1 = *reinterpret_cast<const float4*>(p + 4);
            bfr[step][0] = (__bf16)v0.x; bfr[step][1] = (__bf16)v0.y;
            bfr[step][2] = (__bf16)v0.z; bfr[step][3] = (__bf16)v0.w;
            bfr[step][4] = (__bf16)v1.x; bfr[step][5] = (__bf16)v1.y;
            bfr[step][6] = (__bf16)v1.z; bfr[step][7] = (__bf16)v1.w;
        }

        const float* xls = xl + (size_t)s * 256;
        const float* xrd = xr + (size_t)d * 256;

        float hsum[4] = {0.0f, 0.0f, 0.0f, 0.0f};
#pragma unroll
        for (int cb = 0; cb < 16; cb++) {     /* 16-c block; head = cb>>2 */
            f32x4 acc;
            acc[0] = acc[1] = acc[2] = acc[3] = 0.0f;
            bf16x8 a0 = *reinterpret_cast<const bf16x8*>(&fb[((cb * 2 + 0) * 64 + lane) * 8]);
            bf16x8 a1 = *reinterpret_cast<const bf16x8*>(&fb[((cb * 2 + 1) * 64 + lane) * 8]);
            acc = __builtin_amdgcn_mfma_f32_16x16x32_bf16(a0, bfr[0], acc, 0, 0, 0);
            acc = __builtin_amdgcn_mfma_f32_16x16x32_bf16(a1, bfr[1], acc, 0, 0, 0);

            int cbase = cb * 16 + quad * 4;
            float4 xa = *reinterpret_cast<const float4*>(xls + cbase);
            float4 xb = *reinterpret_cast<const float4*>(xrd + cbase);
            float4 at = *reinterpret_cast<const float4*>(&att_s[cbase]);
            const float* ap = reinterpret_cast<const float*>(&xa);
            const float* bp = reinterpret_cast<const float*>(&xb);
            const float* tp = reinterpret_cast<const float*>(&at);
            float hs = 0.0f;
#pragma unroll
            for (int r = 0; r < 4; r++) {
                float v = acc[r] + ap[r] + bp[r];
                v = (v >= 0.0f) ? v : NEG_SLOPE * v;
                hs = fmaf(v, tp[r], hs);
            }
            hsum[cb >> 2] += hs;
        }
#pragma unroll
        for (int hh = 0; hh < 4; hh++) {
            hsum[hh] += __shfl_xor(hsum[hh], 16, 64);
            hsum[hh] += __shfl_xor(hsum[hh], 32, 64);
        }
        if (quad == 0 && e < NE_TOT) {
            reinterpret_cast<float4*>(logits)[e] =
                make_float4(hsum[0], hsum[1], hsum[2], hsum[3]);
        }
    }
}

/* one wave per node: segment softmax + weighted sum + bias + SiLU + LayerNorm.
   3 passes, each unrolled so loads pipeline (independent iterations). */
__global__ void k_aggregate(const int* __restrict__ ei,
                            const int* __restrict__ row_ptr,
                            const int* __restrict__ eids,
                            const float* __restrict__ logits,
                            const float* __restrict__ xl,
                            const float* __restrict__ bias,
                            const float* __restrict__ gamma,
                            const float* __restrict__ beta,
                            float* __restrict__ hout,
                            float* __restrict__ alpha_out) {
    int node = (blockIdx.x << 2) + (threadIdx.x >> 6);
    int lane = threadIdx.x & 63;
    int h = lane >> 4;
    int b = row_ptr[node], en = row_ptr[node + 1];

    /* pass 1: max (4 independent partials) */
    float m0 = -INFINITY, m1 = -INFINITY, m2 = -INFINITY, m3 = -INFINITY;
    int i = b;
    for (; i + 3 < en; i += 4) {
        int e0 = eids[i], e1 = eids[i + 1], e2 = eids[i + 2], e3 = eids[i + 3];
        m0 = fmaxf(m0, logits[e0 * 4 + h]);
        m1 = fmaxf(m1, logits[e1 * 4 + h]);
        m2 = fmaxf(m2, logits[e2 * 4 + h]);
        m3 = fmaxf(m3, logits[e3 * 4 + h]);
    }
    for (; i < en; i++) m0 = fmaxf(m0, logits[eids[i] * 4 + h]);
    float mh = fmaxf(fmaxf(m0, m1), fmaxf(m2, m3));

    /* pass 2: denom (4 independent partials) */
    float d0 = 0.0f, d1 = 0.0f, d2 = 0.0f, d3 = 0.0f;
    i = b;
    for (; i + 3 < en; i += 4) {
        int e0 = eids[i], e1 = eids[i + 1], e2 = eids[i + 2], e3 = eids[i + 3];
        d0 += __expf(logits[e0 * 4 + h] - mh);
        d1 += __expf(logits[e1 * 4 + h] - mh);
        d2 += __expf(logits[e2 * 4 + h] - mh);
        d3 += __expf(logits[e3 * 4 + h] - mh);
    }
    for (; i < en; i++) d0 += __expf(logits[eids[i] * 4 + h] - mh);
    float rden = 1.0f / ((d0 + d1) + (d2 + d3));

    /* pass 3: alpha + weighted gather (4 accumulators, 4 rows in flight) */
    const float4* xl4p = reinterpret_cast<const float4*>(xl);
    float4 ac0; ac0.x = ac0.y = ac0.z = ac0.w = 0.0f;
    float4 ac1; ac1.x = ac1.y = ac1.z = ac1.w = 0.0f;
    float4 ac2; ac2.x = ac2.y = ac2.z = ac2.w = 0.0f;
    float4 ac3; ac3.x = ac3.y = ac3.z = ac3.w = 0.0f;
    i = b;
    for (; i + 3 < en; i += 4) {
        int e0 = eids[i], e1 = eids[i + 1], e2 = eids[i + 2], e3 = eids[i + 3];
        float al0 = __expf(logits[e0 * 4 + h] - mh) * rden;
        float al1 = __expf(logits[e1 * 4 + h] - mh) * rden;
        float al2 = __expf(logits[e2 * 4 + h] - mh) * rden;
        float al3 = __expf(logits[e3 * 4 + h] - mh) * rden;
        if ((lane & 15) == 0) {
            alpha_out[e0 * 4 + h] = al0;
            alpha_out[e1 * 4 + h] = al1;
            alpha_out[e2 * 4 + h] = al2;
            alpha_out[e3 * 4 + h] = al3;
        }
        int s0 = (e0 < N_EDGES) ? ei[e0] : (e0 - N_EDGES);
        int s1 = (e1 < N_EDGES) ? ei[e1] : (e1 - N_EDGES);
        int s2 = (e2 < N_EDGES) ? ei[e2] : (e2 - N_EDGES);
        int s3 = (e3 < N_EDGES) ? ei[e3] : (e3 - N_EDGES);
        float4 xv0 = xl4p[s0 * 64 + lane];
        float4 xv1 = xl4p[s1 * 64 + lane];
        float4 xv2 = xl4p[s2 * 64 + lane];
        float4 xv3 = xl4p[s3 * 64 + lane];
        ac0.x = fmaf(al0, xv0.x, ac0.x); ac0.y = fmaf(al0, xv0.y, ac0.y);
        ac0.z = fmaf(al0, xv0.z, ac0.z); ac0.w = fmaf(al0, xv0.w, ac0.w);
        ac1.x = fmaf(al1, xv1.x, ac1.x); ac1.y = fmaf(al1, xv1.y, ac1.y);
        ac1.z = fmaf(al1, xv1.z, ac1.z); ac1.w = fmaf(al1, xv1.w, ac1.w);
        ac2.x = fmaf(al2, xv2.x, ac2.x); ac2.y = fmaf(al2, xv2.y, ac2.y);
        ac2.z = fmaf(al2, xv2.z, ac2.z); ac2.w = fmaf(al2, xv2.w, ac2.w);
        ac3.x = fmaf(al3, xv3.x, ac3.x); ac3.y = fmaf(al3, xv3.y, ac3.y);
        ac3.z = fmaf(al3, xv3.z, ac3.z); ac3.w = fmaf(al3, xv3.w, ac3.w);
    }
    for (; i < en; i++) {
        int e = eids[i];
        float al = __expf(logits[e * 4 + h] - mh) * rden;
        if ((lane & 15) == 0) alpha_out[e * 4 + h] = al;
        int s = (e < N_EDGES) ? ei[e] : (e - N_EDGES);
        float4 xv = xl4p[s * 64 + lane];
        ac0.x = fmaf(al, xv.x, ac0.x); ac0.y = fmaf(al, xv.y, ac0.y);
        ac0.z = fmaf(al, xv.z, ac0.z); ac0.w = fmaf(al, xv.w, ac0.w);
    }
    float4 acc;
    acc.x = (ac0.x + ac1.x) + (ac2.x + ac3.x);
    acc.y = (ac0.y + ac1.y) + (ac2.y + ac3.y);
    acc.z = (ac0.z + ac1.z) + (ac2.z + ac3.z);
    acc.w = (ac0.w + ac1.w) + (ac2.w + ac3.w);

    const float4 b4 = reinterpret_cast<const float4*>(bias)[lane];
    float4 hv;
    hv.x = acc.x + b4.x; hv.y = acc.y + b4.y;
    hv.z = acc.z + b4.z; hv.w = acc.w + b4.w;
    /* SiLU */
    hv.x = hv.x / (1.0f + __expf(-hv.x));
    hv.y = hv.y / (1.0f + __expf(-hv.y));
    hv.z = hv.z / (1.0f + __expf(-hv.z));
    hv.w = hv.w / (1.0f + __expf(-hv.w));
    /* LayerNorm over 256 dims spread across 64 lanes x 4 */
    float s1 = hv.x + hv.y + hv.z + hv.w;
    float s2 = hv.x * hv.x + hv.y * hv.y + hv.z * hv.z + hv.w * hv.w;
#pragma unroll
    for (int off = 1; off < 64; off <<= 1) {
        s1 += __shfl_xor(s1, off, 64);
        s2 += __shfl_xor(s2, off, 64);
    }
    float mu = s1 * (1.0f / 256.0f);
    float var = s2 * (1.0f / 256.0f) - mu * mu;
    float rs = rsqrtf(var + LN_EPS);
    const float4 g4 = reinterpret_cast<const float4*>(gamma)[lane];
    const float4 be4 = reinterpret_cast<const float4*>(beta)[lane];
    float4 o;
    o.x = (hv.x - mu) * rs * g4.x + be4.x;
    o.y = (hv.y - mu) * rs * g4.y + be4.y;
    o.z = (hv.z - mu) * rs * g4.z + be4.z;
    o.w = (hv.w - mu) * rs * g4.w + be4.w;
    reinterpret_cast<float4*>(hout)[node * 64 + lane] = o;
}

extern "C" void kernel_launch(void* const* d_in, const int* in_sizes, int n_in,
                              void* d_out, int out_size, void* d_ws, size_t ws_size,
                              hipStream_t stream) {
    (void)in_sizes; (void)n_in; (void)out_size; (void)ws_size;
    const float* x         = (const float*)d_in[0];
    const int*   ei        = (const int*)d_in[1];
    const float* edge_attr = (const float*)d_in[2];
    const float* Wl        = (const float*)d_in[3];
    const float* bl        = (const float*)d_in[4];
    const float* Wr        = (const float*)d_in[5];
    const float* br        = (const float*)d_in[6];
    const float* We        = (const float*)d_in[7];
    const float* att       = (const float*)d_in[8];
    const float* bias      = (const float*)d_in[9];
    const float* gamma     = (const float*)d_in[10];
    const float* beta      = (const float*)d_in[11];

    char* ws = (char*)d_ws;
    int*   cnt     = (int*)(ws + OFF_CNT);
    int*   fill    = (int*)(ws + OFF_FILL);
    int*   row_ptr = (int*)(ws + OFF_ROWPTR);
    int*   eids    = (int*)(ws + OFF_EIDS);
    float* lattr   = (float*)(ws + OFF_LATTR);
    float* xl      = (float*)(ws + OFF_XL);
    float* xr      = (float*)(ws + OFF_XR);
    float* logits  = (float*)(ws + OFF_LOG);

    float* hout      = (float*)d_out;
    float* alpha_out = (float*)d_out + N_NODES * 256;

    hipMemsetAsync(ws + OFF_CNT, 0, 2 * N_NODES * sizeof(int), stream);

    k_count<<<(N_EDGES + 255) / 256, 256, 0, stream>>>(ei, cnt);
    k_scan<<<1, 256, 0, stream>>>(cnt, row_ptr);
    k_fill<<<(NE_TOT + 255) / 256, 256, 0, stream>>>(ei, row_ptr, fill, eids);
    k_loop_attr<<<N_NODES / 4, 256, 0, stream>>>(edge_attr, row_ptr, eids, cnt, lattr);
    k_gemm_xlxr<<<N_NODES / 8, 256, 0, stream>>>(x, Wl, bl, Wr, br, xl, xr);
    k_logits_mfma<<<2579, 256, 0, stream>>>(ei, edge_attr, lattr, xl, xr, We, att, logits);
    k_aggregate<<<N_NODES / 4, 256, 0, stream>>>(ei, row_ptr, eids, logits, xl,
                                                 bias, gamma, beta, hout, alpha_out);
}

// Round 7
// 463.280 us; speedup vs baseline: 1.9256x; 1.2303x over previous
//
#include <hip/hip_runtime.h>

#define N_NODES 10000
#define N_EDGES 320000
#define NE_TOT  330000   /* E + N */
#define NEG_SLOPE 0.2f
#define LN_EPS 1e-5f

/* workspace layout (bytes) */
#define OFF_CNT    0u         /* int[N]            */
#define OFF_FILL   40000u     /* int[N]            */
#define OFF_ROWPTR 80128u     /* int[N+1]          */
#define OFF_EIDS   120320u    /* int[E+N]          */
#define OFF_LATTR  1440512u   /* float[N*64]       */
#define OFF_XLH    4000512u   /* ushort[N*256] bf16 */
#define OFF_XRH    9120512u   /* ushort[N*256] bf16 */
#define OFF_LOG    14240512u  /* float[(E+N)*4], indexed by CSR position */

typedef __bf16 bf16x8 __attribute__((ext_vector_type(8)));
typedef float  f32x4  __attribute__((ext_vector_type(4)));
typedef unsigned short us4 __attribute__((ext_vector_type(4)));

__device__ __forceinline__ float bf2f(unsigned short u) {
    union { unsigned int i; float f; } v;
    v.i = ((unsigned int)u) << 16;
    return v.f;
}
__device__ __forceinline__ unsigned short f2bf(float x) {
    __bf16 b = (__bf16)x;
    return __builtin_bit_cast(unsigned short, b);
}

__global__ void k_count(const int* __restrict__ ei, int* __restrict__ cnt) {
    int e = blockIdx.x * blockDim.x + threadIdx.x;
    if (e < N_EDGES) atomicAdd(&cnt[ei[N_EDGES + e]], 1);
}

__global__ void k_scan(const int* __restrict__ cnt, int* __restrict__ row_ptr) {
    __shared__ int sums[1024];
    int t = threadIdx.x;
    const int CH = 10;   /* 1024*10 >= N */
    int base = t * CH;
    int s = 0;
    for (int i = 0; i < CH; i++) {
        int n = base + i;
        if (n < N_NODES) s += cnt[n] + 1;   /* +1 self loop */
    }
    sums[t] = s;
    __syncthreads();
    for (int off = 1; off < 1024; off <<= 1) {
        int v = (t >= off) ? sums[t - off] : 0;
        __syncthreads();
        sums[t] += v;
        __syncthreads();
    }
    int run = (t == 0) ? 0 : sums[t - 1];
    for (int i = 0; i < CH; i++) {
        int n = base + i;
        if (n < N_NODES) { row_ptr[n] = run; run += cnt[n] + 1; }
    }
    if (t == 1023) row_ptr[N_NODES] = sums[1023];
}

__global__ void k_fill(const int* __restrict__ ei, const int* __restrict__ row_ptr,
                       int* __restrict__ fill, int* __restrict__ eids) {
    int e = blockIdx.x * blockDim.x + threadIdx.x;
    if (e >= NE_TOT) return;
    int d = (e < N_EDGES) ? ei[N_EDGES + e] : (e - N_EDGES);
    int pos = atomicAdd(&fill[d], 1);
    eids[row_ptr[d] + pos] = e;
}

/* one wave per node: mean of incoming edge_attr; 4 rows in flight. */
__global__ void k_loop_attr(const float* __restrict__ edge_attr,
                            const int* __restrict__ row_ptr,
                            const int* __restrict__ eids,
                            const int* __restrict__ cnt,
                            float* __restrict__ lattr) {
    int node = (blockIdx.x << 2) + (threadIdx.x >> 6);
    int lane = threadIdx.x & 63;
    int b = row_ptr[node], en = row_ptr[node + 1];
    float s0 = 0.0f, s1 = 0.0f, s2 = 0.0f, s3 = 0.0f;
    int i = b;
    for (; i + 3 < en; i += 4) {
        int e0 = eids[i], e1 = eids[i + 1], e2 = eids[i + 2], e3 = eids[i + 3];
        int v0 = e0 < N_EDGES, v1 = e1 < N_EDGES, v2 = e2 < N_EDGES, v3 = e3 < N_EDGES;
        float a0 = edge_attr[(size_t)(v0 ? e0 : 0) * 64 + lane];
        float a1 = edge_attr[(size_t)(v1 ? e1 : 0) * 64 + lane];
        float a2 = edge_attr[(size_t)(v2 ? e2 : 0) * 64 + lane];
        float a3 = edge_attr[(size_t)(v3 ? e3 : 0) * 64 + lane];
        s0 += v0 ? a0 : 0.0f;
        s1 += v1 ? a1 : 0.0f;
        s2 += v2 ? a2 : 0.0f;
        s3 += v3 ? a3 : 0.0f;
    }
    for (; i < en; i++) {
        int e = eids[i];
        int v = e < N_EDGES;
        float a = edge_attr[(size_t)(v ? e : 0) * 64 + lane];
        s0 += v ? a : 0.0f;
    }
    float s = (s0 + s1) + (s2 + s3);
    float c = (float)cnt[node];
    lattr[node * 64 + lane] = s / fmaxf(c, 1.0f);
}

/* xl = x@Wl^T + bl ; xr = x@Wr^T + br, stored bf16.  8 nodes/block. */
__global__ void k_gemm_xlxr(const float* __restrict__ x,
                            const float* __restrict__ Wl, const float* __restrict__ bl,
                            const float* __restrict__ Wr, const float* __restrict__ br,
                            unsigned short* __restrict__ xlh,
                            unsigned short* __restrict__ xrh) {
    __shared__ float xs[8][256];
    int t = threadIdx.x;
    int nb = blockIdx.x * 8;
#pragma unroll
    for (int nn = 0; nn < 8; nn++) xs[nn][t] = x[(nb + nn) * 256 + t];
    __syncthreads();

    float accl[8], accr[8];
    float b0 = bl[t], b1 = br[t];
#pragma unroll
    for (int nn = 0; nn < 8; nn++) { accl[nn] = b0; accr[nn] = b1; }

    const float4* wl4 = reinterpret_cast<const float4*>(Wl) + t * 64;
    const float4* wr4 = reinterpret_cast<const float4*>(Wr) + t * 64;
    for (int i = 0; i < 64; i++) {
        float4 wl = wl4[i];
        float4 wr = wr4[i];
#pragma unroll
        for (int nn = 0; nn < 8; nn++) {
            float4 xv = reinterpret_cast<const float4*>(xs[nn])[i];
            accl[nn] = fmaf(xv.x, wl.x, accl[nn]);
            accl[nn] = fmaf(xv.y, wl.y, accl[nn]);
            accl[nn] = fmaf(xv.z, wl.z, accl[nn]);
            accl[nn] = fmaf(xv.w, wl.w, accl[nn]);
            accr[nn] = fmaf(xv.x, wr.x, accr[nn]);
            accr[nn] = fmaf(xv.y, wr.y, accr[nn]);
            accr[nn] = fmaf(xv.z, wr.z, accr[nn]);
            accr[nn] = fmaf(xv.w, wr.w, accr[nn]);
        }
    }
#pragma unroll
    for (int nn = 0; nn < 8; nn++) {
        xlh[(nb + nn) * 256 + t] = f2bf(accl[nn]);
        xrh[(nb + nn) * 256 + t] = f2bf(accr[nn]);
    }
}

/* logits via operand-swapped 16x16x32 MFMA; edges processed in CSR (dst-
   grouped) order so xr rows are L1/L2-hot; xl/xr gathered as bf16 (half
   bytes); logits written by CSR position (sequential for k_aggregate).
   A = We frag (m=c), B = ea frag (n=edge); C: col=lane&15 = edge,
   row=(lane>>4)*4+r = c-in-16-block. */
__global__ __launch_bounds__(256) void k_logits_mfma(
        const int* __restrict__ ei,
        const int* __restrict__ eids,
        const float* __restrict__ edge_attr,
        const float* __restrict__ lattr,
        const unsigned short* __restrict__ xlh,
        const unsigned short* __restrict__ xrh,
        const float* __restrict__ We, const float* __restrict__ att,
        float* __restrict__ logits) {
    __shared__ __bf16 fb[32 * 64 * 8];   /* [f=cb*2+step][lane][8], 32 KB */
    __shared__ float att_s[256];
    int tid = threadIdx.x;

    /* build We fragments (We is [c=256][k=64] row-major) */
    for (int idx = tid; idx < 2048; idx += 256) {
        int f = idx >> 6, ls = idx & 63;
        int cb = f >> 1, step = f & 1;
        int c = cb * 16 + (ls & 15);
        int k = step * 32 + (ls >> 4) * 8;
        const float* w = We + c * 64 + k;
        float4 a0 = *reinterpret_cast<const float4*>(w);
        float4 a1 = *reinterpret_cast<const float4*>(w + 4);
        bf16x8 t;
        t[0] = (__bf16)a0.x; t[1] = (__bf16)a0.y; t[2] = (__bf16)a0.z; t[3] = (__bf16)a0.w;
        t[4] = (__bf16)a1.x; t[5] = (__bf16)a1.y; t[6] = (__bf16)a1.z; t[7] = (__bf16)a1.w;
        *reinterpret_cast<bf16x8*>(&fb[idx * 8]) = t;
    }
    if (tid < 64) {
        reinterpret_cast<float4*>(att_s)[tid] =
            reinterpret_cast<const float4*>(att)[tid];
    }
    __syncthreads();

    int lane = tid & 63;
    int wv = tid >> 6;
    int quad = lane >> 4;
    int ln15 = lane & 15;

    const int ntiles = NE_TOT / 16;   /* 20625, exact */
    for (int t = blockIdx.x * 4 + wv; t < ntiles; t += gridDim.x * 4) {
        int pos = t * 16 + ln15;          /* CSR position */
        int e = eids[pos];
        int s, d;
        const float* row;
        if (e < N_EDGES) {
            s = ei[e]; d = ei[N_EDGES + e];
            row = edge_attr + (size_t)e * 64;
        } else {
            s = e - N_EDGES; d = s;
            row = lattr + (size_t)(e - N_EDGES) * 64;
        }

        /* B fragments: lane holds edge ln15's ea[k], k = step*32 + quad*8 + j */
        bf16x8 bfr[2];
#pragma unroll
        for (int step = 0; step < 2; step++) {
            const float* p = row + step * 32 + quad * 8;
            float4 v0 = *reinterpret_cast<const float4*>(p);
            float4 v1 = *reinterpret_cast<const float4*>(p + 4);
            bfr[step][0] = (__bf16)v0.x; bfr[step][1] = (__bf16)v0.y;
            bfr[step][2] = (__bf16)v0.z; bfr[step][3] = (__bf16)v0.w;
            bfr[step][4] = (__bf16)v1.x; bfr[step][5] = (__bf16)v1.y;
            bfr[step][6] = (__bf16)v1.z; bfr[step][7] = (__bf16)v1.w;
        }

        const unsigned short* xls = xlh + (size_t)s * 256;
        const unsigned short* xrd = xrh + (size_t)d * 256;

        float hsum[4] = {0.0f, 0.0f, 0.0f, 0.0f};
#pragma unroll 4
        for (int cb = 0; cb < 16; cb++) {     /* 16-c block; head = cb>>2 */
            f32x4 acc;
            acc[0] = acc[1] = acc[2] = acc[3] = 0.0f;
            bf16x8 a0 = *reinterpret_cast<const bf16x8*>(&fb[((cb * 2 + 0) * 64 + lane) * 8]);
            bf16x8 a1 = *reinterpret_cast<const bf16x8*>(&fb[((cb * 2 + 1) * 64 + lane) * 8]);
            acc = __builtin_amdgcn_mfma_f32_16x16x32_bf16(a0, bfr[0], acc, 0, 0, 0);
            acc = __builtin_amdgcn_mfma_f32_16x16x32_bf16(a1, bfr[1], acc, 0, 0, 0);

            int cbase = cb * 16 + quad * 4;
            us4 xa = *reinterpret_cast<const us4*>(xls + cbase);
            us4 xb = *reinterpret_cast<const us4*>(xrd + cbase);
            float4 at = *reinterpret_cast<const float4*>(&att_s[cbase]);
            const float* tp = reinterpret_cast<const float*>(&at);
            float hs = 0.0f;
#pragma unroll
            for (int r = 0; r < 4; r++) {
                float v = acc[r] + bf2f(xa[r]) + bf2f(xb[r]);
                v = (v >= 0.0f) ? v : NEG_SLOPE * v;
                hs = fmaf(v, tp[r], hs);
            }
            hsum[cb >> 2] += hs;
        }
#pragma unroll
        for (int hh = 0; hh < 4; hh++) {
            hsum[hh] += __shfl_xor(hsum[hh], 16, 64);
            hsum[hh] += __shfl_xor(hsum[hh], 32, 64);
        }
        if (quad == 0) {
            reinterpret_cast<float4*>(logits)[pos] =
                make_float4(hsum[0], hsum[1], hsum[2], hsum[3]);
        }
    }
}

/* one wave per node: segment softmax + weighted sum + bias + SiLU + LayerNorm.
   logits indexed by CSR position -> passes 1/2 are pure sequential reads. */
__global__ void k_aggregate(const int* __restrict__ ei,
                            const int* __restrict__ row_ptr,
                            const int* __restrict__ eids,
                            const float* __restrict__ logits,
                            const unsigned short* __restrict__ xlh,
                            const float* __restrict__ bias,
                            const float* __restrict__ gamma,
                            const float* __restrict__ beta,
                            float* __restrict__ hout,
                            float* __restrict__ alpha_out) {
    int node = (blockIdx.x << 2) + (threadIdx.x >> 6);
    int lane = threadIdx.x & 63;
    int h = lane >> 4;
    int b = row_ptr[node], en = row_ptr[node + 1];

    /* pass 1: max (sequential logits reads) */
    float m0 = -INFINITY, m1 = -INFINITY, m2 = -INFINITY, m3 = -INFINITY;
    int i = b;
    for (; i + 3 < en; i += 4) {
        m0 = fmaxf(m0, logits[(i + 0) * 4 + h]);
        m1 = fmaxf(m1, logits[(i + 1) * 4 + h]);
        m2 = fmaxf(m2, logits[(i + 2) * 4 + h]);
        m3 = fmaxf(m3, logits[(i + 3) * 4 + h]);
    }
    for (; i < en; i++) m0 = fmaxf(m0, logits[i * 4 + h]);
    float mh = fmaxf(fmaxf(m0, m1), fmaxf(m2, m3));

    /* pass 2: denom */
    float d0 = 0.0f, d1 = 0.0f, d2 = 0.0f, d3 = 0.0f;
    i = b;
    for (; i + 3 < en; i += 4) {
        d0 += __expf(logits[(i + 0) * 4 + h] - mh);
        d1 += __expf(logits[(i + 1) * 4 + h] - mh);
        d2 += __expf(logits[(i + 2) * 4 + h] - mh);
        d3 += __expf(logits[(i + 3) * 4 + h] - mh);
    }
    for (; i < en; i++) d0 += __expf(logits[i * 4 + h] - mh);
    float rden = 1.0f / ((d0 + d1) + (d2 + d3));

    /* pass 3: alpha + weighted bf16 gather (4 rows in flight) */
    int c0 = lane * 4;
    float4 ac0; ac0.x = ac0.y = ac0.z = ac0.w = 0.0f;
    float4 ac1; ac1.x = ac1.y = ac1.z = ac1.w = 0.0f;
    float4 ac2; ac2.x = ac2.y = ac2.z = ac2.w = 0.0f;
    float4 ac3; ac3.x = ac3.y = ac3.z = ac3.w = 0.0f;
    i = b;
    for (; i + 3 < en; i += 4) {
        int e0 = eids[i], e1 = eids[i + 1], e2 = eids[i + 2], e3 = eids[i + 3];
        float al0 = __expf(logits[(i + 0) * 4 + h] - mh) * rden;
        float al1 = __expf(logits[(i + 1) * 4 + h] - mh) * rden;
        float al2 = __expf(logits[(i + 2) * 4 + h] - mh) * rden;
        float al3 = __expf(logits[(i + 3) * 4 + h] - mh) * rden;
        if ((lane & 15) == 0) {
            alpha_out[e0 * 4 + h] = al0;
            alpha_out[e1 * 4 + h] = al1;
            alpha_out[e2 * 4 + h] = al2;
            alpha_out[e3 * 4 + h] = al3;
        }
        int s0 = (e0 < N_EDGES) ? ei[e0] : (e0 - N_EDGES);
        int s1 = (e1 < N_EDGES) ? ei[e1] : (e1 - N_EDGES);
        int s2 = (e2 < N_EDGES) ? ei[e2] : (e2 - N_EDGES);
        int s3 = (e3 < N_EDGES) ? ei[e3] : (e3 - N_EDGES);
        us4 x0 = *reinterpret_cast<const us4*>(xlh + (size_t)s0 * 256 + c0);
        us4 x1 = *reinterpret_cast<const us4*>(xlh + (size_t)s1 * 256 + c0);
        us4 x2 = *reinterpret_cast<const us4*>(xlh + (size_t)s2 * 256 + c0);
        us4 x3 = *reinterpret_cast<const us4*>(xlh + (size_t)s3 * 256 + c0);
        ac0.x = fmaf(al0, bf2f(x0[0]), ac0.x); ac0.y = fmaf(al0, bf2f(x0[1]), ac0.y);
        ac0.z = fmaf(al0, bf2f(x0[2]), ac0.z); ac0.w = fmaf(al0, bf2f(x0[3]), ac0.w);
        ac1.x = fmaf(al1, bf2f(x1[0]), ac1.x); ac1.y = fmaf(al1, bf2f(x1[1]), ac1.y);
        ac1.z = fmaf(al1, bf2f(x1[2]), ac1.z); ac1.w = fmaf(al1, bf2f(x1[3]), ac1.w);
        ac2.x = fmaf(al2, bf2f(x2[0]), ac2.x); ac2.y = fmaf(al2, bf2f(x2[1]), ac2.y);
        ac2.z = fmaf(al2, bf2f(x2[2]), ac2.z); ac2.w = fmaf(al2, bf2f(x2[3]), ac2.w);
        ac3.x = fmaf(al3, bf2f(x3[0]), ac3.x); ac3.y = fmaf(al3, bf2f(x3[1]), ac3.y);
        ac3.z = fmaf(al3, bf2f(x3[2]), ac3.z); ac3.w = fmaf(al3, bf2f(x3[3]), ac3.w);
    }
    for (; i < en; i++) {
        int e = eids[i];
        float al = __expf(logits[i * 4 + h] - mh) * rden;
        if ((lane & 15) == 0) alpha_out[e * 4 + h] = al;
        int s = (e < N_EDGES) ? ei[e] : (e - N_EDGES);
        us4 xv = *reinterpret_cast<const us4*>(xlh + (size_t)s * 256 + c0);
        ac0.x = fmaf(al, bf2f(xv[0]), ac0.x); ac0.y = fmaf(al, bf2f(xv[1]), ac0.y);
        ac0.z = fmaf(al, bf2f(xv[2]), ac0.z); ac0.w = fmaf(al, bf2f(xv[3]), ac0.w);
    }
    float4 acc;
    acc.x = (ac0.x + ac1.x) + (ac2.x + ac3.x);
    acc.y = (ac0.y + ac1.y) + (ac2.y + ac3.y);
    acc.z = (ac0.z + ac1.z) + (ac2.z + ac3.z);
    acc.w = (ac0.w + ac1.w) + (ac2.w + ac3.w);

    const float4 b4 = reinterpret_cast<const float4*>(bias)[lane];
    float4 hv;
    hv.x = acc.x + b4.x; hv.y = acc.y + b4.y;
    hv.z = acc.z + b4.z; hv.w = acc.w + b4.w;
    /* SiLU */
    hv.x = hv.x / (1.0f + __expf(-hv.x));
    hv.y = hv.y / (1.0f + __expf(-hv.y));
    hv.z = hv.z / (1.0f + __expf(-hv.z));
    hv.w = hv.w / (1.0f + __expf(-hv.w));
    /* LayerNorm over 256 dims spread across 64 lanes x 4 */
    float s1 = hv.x + hv.y + hv.z + hv.w;
    float s2 = hv.x * hv.x + hv.y * hv.y + hv.z * hv.z + hv.w * hv.w;
#pragma unroll
    for (int off = 1; off < 64; off <<= 1) {
        s1 += __shfl_xor(s1, off, 64);
        s2 += __shfl_xor(s2, off, 64);
    }
    float mu = s1 * (1.0f / 256.0f);
    float var = s2 * (1.0f / 256.0f) - mu * mu;
    float rs = rsqrtf(var + LN_EPS);
    const float4 g4 = reinterpret_cast<const float4*>(gamma)[lane];
    const float4 be4 = reinterpret_cast<const float4*>(beta)[lane];
    float4 o;
    o.x = (hv.x - mu) * rs * g4.x + be4.x;
    o.y = (hv.y - mu) * rs * g4.y + be4.y;
    o.z = (hv.z - mu) * rs * g4.z + be4.z;
    o.w = (hv.w - mu) * rs * g4.w + be4.w;
    reinterpret_cast<float4*>(hout)[node * 64 + lane] = o;
}

extern "C" void kernel_launch(void* const* d_in, const int* in_sizes, int n_in,
                              void* d_out, int out_size, void* d_ws, size_t ws_size,
                              hipStream_t stream) {
    (void)in_sizes; (void)n_in; (void)out_size; (void)ws_size;
    const float* x         = (const float*)d_in[0];
    const int*   ei        = (const int*)d_in[1];
    const float* edge_attr = (const float*)d_in[2];
    const float* Wl        = (const float*)d_in[3];
    const float* bl        = (const float*)d_in[4];
    const float* Wr        = (const float*)d_in[5];
    const float* br        = (const float*)d_in[6];
    const float* We        = (const float*)d_in[7];
    const float* att       = (const float*)d_in[8];
    const float* bias      = (const float*)d_in[9];
    const float* gamma     = (const float*)d_in[10];
    const float* beta      = (const float*)d_in[11];

    char* ws = (char*)d_ws;
    int*   cnt     = (int*)(ws + OFF_CNT);
    int*   fill    = (int*)(ws + OFF_FILL);
    int*   row_ptr = (int*)(ws + OFF_ROWPTR);
    int*   eids    = (int*)(ws + OFF_EIDS);
    float* lattr   = (float*)(ws + OFF_LATTR);
    unsigned short* xlh = (unsigned short*)(ws + OFF_XLH);
    unsigned short* xrh = (unsigned short*)(ws + OFF_XRH);
    float* logits  = (float*)(ws + OFF_LOG);

    float* hout      = (float*)d_out;
    float* alpha_out = (float*)d_out + N_NODES * 256;

    hipMemsetAsync(ws + OFF_CNT, 0, 2 * N_NODES * sizeof(int), stream);

    k_count<<<(N_EDGES + 255) / 256, 256, 0, stream>>>(ei, cnt);
    k_scan<<<1, 1024, 0, stream>>>(cnt, row_ptr);
    k_fill<<<(NE_TOT + 255) / 256, 256, 0, stream>>>(ei, row_ptr, fill, eids);
    k_loop_attr<<<N_NODES / 4, 256, 0, stream>>>(edge_attr, row_ptr, eids, cnt, lattr);
    k_gemm_xlxr<<<N_NODES / 8, 256, 0, stream>>>(x, Wl, bl, Wr, br, xlh, xrh);
    k_logits_mfma<<<2579, 256, 0, stream>>>(ei, eids, edge_attr, lattr, xlh, xrh,
                                            We, att, logits);
    k_aggregate<<<N_NODES / 4, 256, 0, stream>>>(ei, row_ptr, eids, logits, xlh,
                                                 bias, gamma, beta, hout, alpha_out);
}

// Round 8
// 379.428 us; speedup vs baseline: 2.3511x; 1.2210x over previous
//
#include <hip/hip_runtime.h>

#define N_NODES 10000
#define N_EDGES 320000
#define NE_TOT  330000   /* E + N */
#define NEG_SLOPE 0.2f
#define LN_EPS 1e-5f

/* workspace layout (bytes) */
#define OFF_CNT    0u         /* int[N]            */
#define OFF_FILL   40000u     /* int[N]            */
#define OFF_ROWPTR 80128u     /* int[N+1]          */
#define OFF_EIDS   120320u    /* int[E+N]          */
#define OFF_LATTR  1440512u   /* float[N*64]       */
#define OFF_XLH    4000512u   /* ushort[N*256] bf16 */
#define OFF_XRH    9120512u   /* ushort[N*256] bf16 */
#define OFF_LOG    14240512u  /* float[(E+N)*4], indexed by CSR position */
#define OFF_WLF    19520512u  /* ushort[8192*8] bf16 Wl fragments */
#define OFF_WRF    19651584u  /* ushort[8192*8] bf16 Wr fragments */

typedef __bf16 bf16x8 __attribute__((ext_vector_type(8)));
typedef float  f32x4  __attribute__((ext_vector_type(4)));
typedef unsigned short us4 __attribute__((ext_vector_type(4)));

__device__ __forceinline__ float bf2f(unsigned short u) {
    union { unsigned int i; float f; } v;
    v.i = ((unsigned int)u) << 16;
    return v.f;
}
__device__ __forceinline__ unsigned short f2bf(float x) {
    __bf16 b = (__bf16)x;
    return __builtin_bit_cast(unsigned short, b);
}
__device__ __forceinline__ bf16x8 cvt8(const float* p) {
    float4 v0 = *reinterpret_cast<const float4*>(p);
    float4 v1 = *reinterpret_cast<const float4*>(p + 4);
    bf16x8 t;
    t[0] = (__bf16)v0.x; t[1] = (__bf16)v0.y; t[2] = (__bf16)v0.z; t[3] = (__bf16)v0.w;
    t[4] = (__bf16)v1.x; t[5] = (__bf16)v1.y; t[6] = (__bf16)v1.z; t[7] = (__bf16)v1.w;
    return t;
}

__global__ void k_count(const int* __restrict__ ei, int* __restrict__ cnt) {
    int e = blockIdx.x * blockDim.x + threadIdx.x;
    if (e < N_EDGES) atomicAdd(&cnt[ei[N_EDGES + e]], 1);
}

__global__ void k_scan(const int* __restrict__ cnt, int* __restrict__ row_ptr) {
    __shared__ int sums[1024];
    int t = threadIdx.x;
    const int CH = 10;
    int base = t * CH;
    int s = 0;
    for (int i = 0; i < CH; i++) {
        int n = base + i;
        if (n < N_NODES) s += cnt[n] + 1;   /* +1 self loop */
    }
    sums[t] = s;
    __syncthreads();
    for (int off = 1; off < 1024; off <<= 1) {
        int v = (t >= off) ? sums[t - off] : 0;
        __syncthreads();
        sums[t] += v;
        __syncthreads();
    }
    int run = (t == 0) ? 0 : sums[t - 1];
    for (int i = 0; i < CH; i++) {
        int n = base + i;
        if (n < N_NODES) { row_ptr[n] = run; run += cnt[n] + 1; }
    }
    if (t == 1023) row_ptr[N_NODES] = sums[1023];
}

__global__ void k_fill(const int* __restrict__ ei, const int* __restrict__ row_ptr,
                       int* __restrict__ fill, int* __restrict__ eids) {
    int e = blockIdx.x * blockDim.x + threadIdx.x;
    if (e >= NE_TOT) return;
    int d = (e < N_EDGES) ? ei[N_EDGES + e] : (e - N_EDGES);
    int pos = atomicAdd(&fill[d], 1);
    eids[row_ptr[d] + pos] = e;
}

/* one wave per node: mean of incoming edge_attr; 4 rows in flight. */
__global__ void k_loop_attr(const float* __restrict__ edge_attr,
                            const int* __restrict__ row_ptr,
                            const int* __restrict__ eids,
                            const int* __restrict__ cnt,
                            float* __restrict__ lattr) {
    int node = (blockIdx.x << 2) + (threadIdx.x >> 6);
    int lane = threadIdx.x & 63;
    int b = row_ptr[node], en = row_ptr[node + 1];
    float s0 = 0.0f, s1 = 0.0f, s2 = 0.0f, s3 = 0.0f;
    int i = b;
    for (; i + 3 < en; i += 4) {
        int e0 = eids[i], e1 = eids[i + 1], e2 = eids[i + 2], e3 = eids[i + 3];
        int v0 = e0 < N_EDGES, v1 = e1 < N_EDGES, v2 = e2 < N_EDGES, v3 = e3 < N_EDGES;
        float a0 = edge_attr[(size_t)(v0 ? e0 : 0) * 64 + lane];
        float a1 = edge_attr[(size_t)(v1 ? e1 : 0) * 64 + lane];
        float a2 = edge_attr[(size_t)(v2 ? e2 : 0) * 64 + lane];
        float a3 = edge_attr[(size_t)(v3 ? e3 : 0) * 64 + lane];
        s0 += v0 ? a0 : 0.0f;
        s1 += v1 ? a1 : 0.0f;
        s2 += v2 ? a2 : 0.0f;
        s3 += v3 ? a3 : 0.0f;
    }
    for (; i < en; i++) {
        int e = eids[i];
        int v = e < N_EDGES;
        float a = edge_attr[(size_t)(v ? e : 0) * 64 + lane];
        s0 += v ? a : 0.0f;
    }
    float s = (s0 + s1) + (s2 + s3);
    float c = (float)cnt[node];
    lattr[node * 64 + lane] = s / fmaxf(c, 1.0f);
}

/* convert Wl/Wr (fp32 [c=256][k=256]) to bf16 MFMA A-fragment order:
   entry idx = (ct*8 + t)*64 + lane holds W[c=ct*16+(lane&15)]
   [k = t*32 + (lane>>4)*8 + j], j=0..7.  8192 entries per matrix. */
__global__ void k_prep_wfrag(const float* __restrict__ Wl,
                             const float* __restrict__ Wr,
                             unsigned short* __restrict__ wlf,
                             unsigned short* __restrict__ wrf) {
    int idx = blockIdx.x * 256 + threadIdx.x;
    if (idx >= 8192) return;
    int ln = idx & 63;
    int ts = (idx >> 6) & 7;
    int ct = idx >> 9;
    int c = ct * 16 + (ln & 15);
    int k0 = ts * 32 + (ln >> 4) * 8;
    *reinterpret_cast<bf16x8*>(wlf + (size_t)idx * 8) = cvt8(Wl + (size_t)c * 256 + k0);
    *reinterpret_cast<bf16x8*>(wrf + (size_t)idx * 8) = cvt8(Wr + (size_t)c * 256 + k0);
}

/* xl/xr projection on MFMA: block = 16 nodes, 4 waves; wave wv covers
   c-tiles wv*4..wv*4+3 for BOTH Wl and Wr.  x staged once per block in LDS
   as B-fragments (bf16); W fragments read from prebuilt global arrays
   (coalesced dwordx4, L2-hot).  C: col=lane&15 = node, row=quad*4+r = c. */
__global__ __launch_bounds__(256) void k_gemm_mfma(
        const float* __restrict__ x,
        const float* __restrict__ bl, const float* __restrict__ br,
        const unsigned short* __restrict__ wlf,
        const unsigned short* __restrict__ wrf,
        unsigned short* __restrict__ xlh,
        unsigned short* __restrict__ xrh) {
    __shared__ __bf16 xs[8 * 64 * 8];   /* [t][lane][8], 8 KB */
    int tid = threadIdx.x;
    int nb = blockIdx.x * 16;

    for (int f = tid; f < 512; f += 256) {
        int t = f >> 6, ln = f & 63;
        int node = nb + (ln & 15);
        int k0 = t * 32 + (ln >> 4) * 8;
        *reinterpret_cast<bf16x8*>(&xs[f * 8]) = cvt8(x + (size_t)node * 256 + k0);
    }
    __syncthreads();

    int lane = tid & 63;
    int wv = tid >> 6;
    int quad = lane >> 4;
    int ln15 = lane & 15;

    bf16x8 bfr[8];
#pragma unroll
    for (int t = 0; t < 8; t++)
        bfr[t] = *reinterpret_cast<const bf16x8*>(&xs[(t * 64 + lane) * 8]);

    int node = nb + ln15;
#pragma unroll
    for (int ci = 0; ci < 4; ci++) {
        int ct = wv * 4 + ci;
        f32x4 accl, accr;
        accl[0] = accl[1] = accl[2] = accl[3] = 0.0f;
        accr[0] = accr[1] = accr[2] = accr[3] = 0.0f;
#pragma unroll
        for (int t = 0; t < 8; t++) {
            bf16x8 al = *reinterpret_cast<const bf16x8*>(
                wlf + ((size_t)(ct * 8 + t) * 64 + lane) * 8);
            accl = __builtin_amdgcn_mfma_f32_16x16x32_bf16(al, bfr[t], accl, 0, 0, 0);
        }
#pragma unroll
        for (int t = 0; t < 8; t++) {
            bf16x8 ar = *reinterpret_cast<const bf16x8*>(
                wrf + ((size_t)(ct * 8 + t) * 64 + lane) * 8);
            accr = __builtin_amdgcn_mfma_f32_16x16x32_bf16(ar, bfr[t], accr, 0, 0, 0);
        }
        int cbase = ct * 16 + quad * 4;
        float4 blv = *reinterpret_cast<const float4*>(bl + cbase);
        float4 brv = *reinterpret_cast<const float4*>(br + cbase);
        us4 ol, orr;
        ol[0] = f2bf(accl[0] + blv.x); ol[1] = f2bf(accl[1] + blv.y);
        ol[2] = f2bf(accl[2] + blv.z); ol[3] = f2bf(accl[3] + blv.w);
        orr[0] = f2bf(accr[0] + brv.x); orr[1] = f2bf(accr[1] + brv.y);
        orr[2] = f2bf(accr[2] + brv.z); orr[3] = f2bf(accr[3] + brv.w);
        *reinterpret_cast<us4*>(xlh + (size_t)node * 256 + cbase) = ol;
        *reinterpret_cast<us4*>(xrh + (size_t)node * 256 + cbase) = orr;
    }
}

/* logits via operand-swapped 16x16x32 MFMA; edges in CSR order (xr L2-hot),
   xl/xr gathered bf16, logits stored by CSR position. */
__global__ __launch_bounds__(256) void k_logits_mfma(
        const int* __restrict__ ei,
        const int* __restrict__ eids,
        const float* __restrict__ edge_attr,
        const float* __restrict__ lattr,
        const unsigned short* __restrict__ xlh,
        const unsigned short* __restrict__ xrh,
        const float* __restrict__ We, const float* __restrict__ att,
        float* __restrict__ logits) {
    __shared__ __bf16 fb[32 * 64 * 8];   /* [f=cb*2+step][lane][8], 32 KB */
    __shared__ float att_s[256];
    int tid = threadIdx.x;

    for (int idx = tid; idx < 2048; idx += 256) {
        int f = idx >> 6, ls = idx & 63;
        int cb = f >> 1, step = f & 1;
        int c = cb * 16 + (ls & 15);
        int k = step * 32 + (ls >> 4) * 8;
        *reinterpret_cast<bf16x8*>(&fb[idx * 8]) = cvt8(We + (size_t)c * 64 + k);
    }
    if (tid < 64) {
        reinterpret_cast<float4*>(att_s)[tid] =
            reinterpret_cast<const float4*>(att)[tid];
    }
    __syncthreads();

    int lane = tid & 63;
    int wv = tid >> 6;
    int quad = lane >> 4;
    int ln15 = lane & 15;

    const int ntiles = NE_TOT / 16;   /* 20625, exact */
    for (int t = blockIdx.x * 4 + wv; t < ntiles; t += gridDim.x * 4) {
        int pos = t * 16 + ln15;          /* CSR position */
        int e = eids[pos];
        int s, d;
        const float* row;
        if (e < N_EDGES) {
            s = ei[e]; d = ei[N_EDGES + e];
            row = edge_attr + (size_t)e * 64;
        } else {
            s = e - N_EDGES; d = s;
            row = lattr + (size_t)(e - N_EDGES) * 64;
        }

        bf16x8 bfr[2];
#pragma unroll
        for (int step = 0; step < 2; step++)
            bfr[step] = cvt8(row + step * 32 + quad * 8);

        const unsigned short* xls = xlh + (size_t)s * 256;
        const unsigned short* xrd = xrh + (size_t)d * 256;

        float hsum[4] = {0.0f, 0.0f, 0.0f, 0.0f};
#pragma unroll 4
        for (int cb = 0; cb < 16; cb++) {
            f32x4 acc;
            acc[0] = acc[1] = acc[2] = acc[3] = 0.0f;
            bf16x8 a0 = *reinterpret_cast<const bf16x8*>(&fb[((cb * 2 + 0) * 64 + lane) * 8]);
            bf16x8 a1 = *reinterpret_cast<const bf16x8*>(&fb[((cb * 2 + 1) * 64 + lane) * 8]);
            acc = __builtin_amdgcn_mfma_f32_16x16x32_bf16(a0, bfr[0], acc, 0, 0, 0);
            acc = __builtin_amdgcn_mfma_f32_16x16x32_bf16(a1, bfr[1], acc, 0, 0, 0);

            int cbase = cb * 16 + quad * 4;
            us4 xa = *reinterpret_cast<const us4*>(xls + cbase);
            us4 xb = *reinterpret_cast<const us4*>(xrd + cbase);
            float4 at = *reinterpret_cast<const float4*>(&att_s[cbase]);
            const float* tp = reinterpret_cast<const float*>(&at);
            float hs = 0.0f;
#pragma unroll
            for (int r = 0; r < 4; r++) {
                float v = acc[r] + bf2f(xa[r]) + bf2f(xb[r]);
                v = (v >= 0.0f) ? v : NEG_SLOPE * v;
                hs = fmaf(v, tp[r], hs);
            }
            hsum[cb >> 2] += hs;
        }
#pragma unroll
        for (int hh = 0; hh < 4; hh++) {
            hsum[hh] += __shfl_xor(hsum[hh], 16, 64);
            hsum[hh] += __shfl_xor(hsum[hh], 32, 64);
        }
        if (quad == 0) {
            reinterpret_cast<float4*>(logits)[pos] =
                make_float4(hsum[0], hsum[1], hsum[2], hsum[3]);
        }
    }
}

/* one wave per node: segment softmax + weighted sum + bias + SiLU + LayerNorm. */
__global__ void k_aggregate(const int* __restrict__ ei,
                            const int* __restrict__ row_ptr,
                            const int* __restrict__ eids,
                            const float* __restrict__ logits,
                            const unsigned short* __restrict__ xlh,
                            const float* __restrict__ bias,
                            const float* __restrict__ gamma,
                            const float* __restrict__ beta,
                            float* __restrict__ hout,
                            float* __restrict__ alpha_out) {
    int node = (blockIdx.x << 2) + (threadIdx.x >> 6);
    int lane = threadIdx.x & 63;
    int h = lane >> 4;
    int b = row_ptr[node], en = row_ptr[node + 1];

    float m0 = -INFINITY, m1 = -INFINITY, m2 = -INFINITY, m3 = -INFINITY;
    int i = b;
    for (; i + 3 < en; i += 4) {
        m0 = fmaxf(m0, logits[(i + 0) * 4 + h]);
        m1 = fmaxf(m1, logits[(i + 1) * 4 + h]);
        m2 = fmaxf(m2, logits[(i + 2) * 4 + h]);
        m3 = fmaxf(m3, logits[(i + 3) * 4 + h]);
    }
    for (; i < en; i++) m0 = fmaxf(m0, logits[i * 4 + h]);
    float mh = fmaxf(fmaxf(m0, m1), fmaxf(m2, m3));

    float d0 = 0.0f, d1 = 0.0f, d2 = 0.0f, d3 = 0.0f;
    i = b;
    for (; i + 3 < en; i += 4) {
        d0 += __expf(logits[(i + 0) * 4 + h] - mh);
        d1 += __expf(logits[(i + 1) * 4 + h] - mh);
        d2 += __expf(logits[(i + 2) * 4 + h] - mh);
        d3 += __expf(logits[(i + 3) * 4 + h] - mh);
    }
    for (; i < en; i++) d0 += __expf(logits[i * 4 + h] - mh);
    float rden = 1.0f / ((d0 + d1) + (d2 + d3));

    int c0 = lane * 4;
    float4 ac0; ac0.x = ac0.y = ac0.z = ac0.w = 0.0f;
    float4 ac1; ac1.x = ac1.y = ac1.z = ac1.w = 0.0f;
    float4 ac2; ac2.x = ac2.y = ac2.z = ac2.w = 0.0f;
    float4 ac3; ac3.x = ac3.y = ac3.z = ac3.w = 0.0f;
    i = b;
    for (; i + 3 < en; i += 4) {
        int e0 = eids[i], e1 = eids[i + 1], e2 = eids[i + 2], e3 = eids[i + 3];
        float al0 = __expf(logits[(i + 0) * 4 + h] - mh) * rden;
        float al1 = __expf(logits[(i + 1) * 4 + h] - mh) * rden;
        float al2 = __expf(logits[(i + 2) * 4 + h] - mh) * rden;
        float al3 = __expf(logits[(i + 3) * 4 + h] - mh) * rden;
        if ((lane & 15) == 0) {
            alpha_out[e0 * 4 + h] = al0;
            alpha_out[e1 * 4 + h] = al1;
            alpha_out[e2 * 4 + h] = al2;
            alpha_out[e3 * 4 + h] = al3;
        }
        int s0 = (e0 < N_EDGES) ? ei[e0] : (e0 - N_EDGES);
        int s1 = (e1 < N_EDGES) ? ei[e1] : (e1 - N_EDGES);
        int s2 = (e2 < N_EDGES) ? ei[e2] : (e2 - N_EDGES);
        int s3 = (e3 < N_EDGES) ? ei[e3] : (e3 - N_EDGES);
        us4 x0 = *reinterpret_cast<const us4*>(xlh + (size_t)s0 * 256 + c0);
        us4 x1 = *reinterpret_cast<const us4*>(xlh + (size_t)s1 * 256 + c0);
        us4 x2 = *reinterpret_cast<const us4*>(xlh + (size_t)s2 * 256 + c0);
        us4 x3 = *reinterpret_cast<const us4*>(xlh + (size_t)s3 * 256 + c0);
        ac0.x = fmaf(al0, bf2f(x0[0]), ac0.x); ac0.y = fmaf(al0, bf2f(x0[1]), ac0.y);
        ac0.z = fmaf(al0, bf2f(x0[2]), ac0.z); ac0.w = fmaf(al0, bf2f(x0[3]), ac0.w);
        ac1.x = fmaf(al1, bf2f(x1[0]), ac1.x); ac1.y = fmaf(al1, bf2f(x1[1]), ac1.y);
        ac1.z = fmaf(al1, bf2f(x1[2]), ac1.z); ac1.w = fmaf(al1, bf2f(x1[3]), ac1.w);
        ac2.x = fmaf(al2, bf2f(x2[0]), ac2.x); ac2.y = fmaf(al2, bf2f(x2[1]), ac2.y);
        ac2.z = fmaf(al2, bf2f(x2[2]), ac2.z); ac2.w = fmaf(al2, bf2f(x2[3]), ac2.w);
        ac3.x = fmaf(al3, bf2f(x3[0]), ac3.x); ac3.y = fmaf(al3, bf2f(x3[1]), ac3.y);
        ac3.z = fmaf(al3, bf2f(x3[2]), ac3.z); ac3.w = fmaf(al3, bf2f(x3[3]), ac3.w);
    }
    for (; i < en; i++) {
        int e = eids[i];
        float al = __expf(logits[i * 4 + h] - mh) * rden;
        if ((lane & 15) == 0) alpha_out[e * 4 + h] = al;
        int s = (e < N_EDGES) ? ei[e] : (e - N_EDGES);
        us4 xv = *reinterpret_cast<const us4*>(xlh + (size_t)s * 256 + c0);
        ac0.x = fmaf(al, bf2f(xv[0]), ac0.x); ac0.y = fmaf(al, bf2f(xv[1]), ac0.y);
        ac0.z = fmaf(al, bf2f(xv[2]), ac0.z); ac0.w = fmaf(al, bf2f(xv[3]), ac0.w);
    }
    float4 acc;
    acc.x = (ac0.x + ac1.x) + (ac2.x + ac3.x);
    acc.y = (ac0.y + ac1.y) + (ac2.y + ac3.y);
    acc.z = (ac0.z + ac1.z) + (ac2.z + ac3.z);
    acc.w = (ac0.w + ac1.w) + (ac2.w + ac3.w);

    const float4 b4 = reinterpret_cast<const float4*>(bias)[lane];
    float4 hv;
    hv.x = acc.x + b4.x; hv.y = acc.y + b4.y;
    hv.z = acc.z + b4.z; hv.w = acc.w + b4.w;
    hv.x = hv.x / (1.0f + __expf(-hv.x));
    hv.y = hv.y / (1.0f + __expf(-hv.y));
    hv.z = hv.z / (1.0f + __expf(-hv.z));
    hv.w = hv.w / (1.0f + __expf(-hv.w));
    float s1 = hv.x + hv.y + hv.z + hv.w;
    float s2 = hv.x * hv.x + hv.y * hv.y + hv.z * hv.z + hv.w * hv.w;
#pragma unroll
    for (int off = 1; off < 64; off <<= 1) {
        s1 += __shfl_xor(s1, off, 64);
        s2 += __shfl_xor(s2, off, 64);
    }
    float mu = s1 * (1.0f / 256.0f);
    float var = s2 * (1.0f / 256.0f) - mu * mu;
    float rs = rsqrtf(var + LN_EPS);
    const float4 g4 = reinterpret_cast<const float4*>(gamma)[lane];
    const float4 be4 = reinterpret_cast<const float4*>(beta)[lane];
    float4 o;
    o.x = (hv.x - mu) * rs * g4.x + be4.x;
    o.y = (hv.y - mu) * rs * g4.y + be4.y;
    o.z = (hv.z - mu) * rs * g4.z + be4.z;
    o.w = (hv.w - mu) * rs * g4.w + be4.w;
    reinterpret_cast<float4*>(hout)[node * 64 + lane] = o;
}

extern "C" void kernel_launch(void* const* d_in, const int* in_sizes, int n_in,
                              void* d_out, int out_size, void* d_ws, size_t ws_size,
                              hipStream_t stream) {
    (void)in_sizes; (void)n_in; (void)out_size; (void)ws_size;
    const float* x         = (const float*)d_in[0];
    const int*   ei        = (const int*)d_in[1];
    const float* edge_attr = (const float*)d_in[2];
    const float* Wl        = (const float*)d_in[3];
    const float* bl        = (const float*)d_in[4];
    const float* Wr        = (const float*)d_in[5];
    const float* br        = (const float*)d_in[6];
    const float* We        = (const float*)d_in[7];
    const float* att       = (const float*)d_in[8];
    const float* bias      = (const float*)d_in[9];
    const float* gamma     = (const float*)d_in[10];
    const float* beta      = (const float*)d_in[11];

    char* ws = (char*)d_ws;
    int*   cnt     = (int*)(ws + OFF_CNT);
    int*   fill    = (int*)(ws + OFF_FILL);
    int*   row_ptr = (int*)(ws + OFF_ROWPTR);
    int*   eids    = (int*)(ws + OFF_EIDS);
    float* lattr   = (float*)(ws + OFF_LATTR);
    unsigned short* xlh = (unsigned short*)(ws + OFF_XLH);
    unsigned short* xrh = (unsigned short*)(ws + OFF_XRH);
    float* logits  = (float*)(ws + OFF_LOG);
    unsigned short* wlf = (unsigned short*)(ws + OFF_WLF);
    unsigned short* wrf = (unsigned short*)(ws + OFF_WRF);

    float* hout      = (float*)d_out;
    float* alpha_out = (float*)d_out + N_NODES * 256;

    hipMemsetAsync(ws + OFF_CNT, 0, 2 * N_NODES * sizeof(int), stream);

    k_count<<<(N_EDGES + 255) / 256, 256, 0, stream>>>(ei, cnt);
    k_scan<<<1, 1024, 0, stream>>>(cnt, row_ptr);
    k_prep_wfrag<<<32, 256, 0, stream>>>(Wl, Wr, wlf, wrf);
    k_fill<<<(NE_TOT + 255) / 256, 256, 0, stream>>>(ei, row_ptr, fill, eids);
    k_gemm_mfma<<<N_NODES / 16, 256, 0, stream>>>(x, bl, br, wlf, wrf, xlh, xrh);
    k_loop_attr<<<N_NODES / 4, 256, 0, stream>>>(edge_attr, row_ptr, eids, cnt, lattr);
    k_logits_mfma<<<2579, 256, 0, stream>>>(ei, eids, edge_attr, lattr, xlh, xrh,
                                            We, att, logits);
    k_aggregate<<<N_NODES / 4, 256, 0, stream>>>(ei, row_ptr, eids, logits, xlh,
                                                 bias, gamma, beta, hout, alpha_out);
}